// Round 1
// baseline (22.116 us; speedup 1.0000x reference)
//
#include <hip/hip_runtime.h>

// BatchedFoveator: output[b,t,c,i,j] = mean of image[b,c, cy+s*i : +s, cx+s*j : +s]
// B=32, C=3, IMG=512, NT=160 tokens (64 @s=1, 48 @s=2, 48 @s=4), 16x16 pixels/token.

#define IMG     512
#define NTOK    160
#define NB      32
#define NC      3

// Decode token index -> (corner_x, corner_y, stride). Matches the reference's
// _precompute_tokens(): level 0 = full 8x8 grid; levels 1,2 = 8x8 grid minus
// the central 4x4 (ring), enumerated as rows 0-1, then (j=0,1,6,7) for rows
// 2-5, then rows 6-7.
__device__ __forceinline__ void token_params(int t, int& cx, int& cy, int& s) {
    if (t < 64) {
        int i = t >> 3, j = t & 7;
        cx = 192 + 16 * j;
        cy = 192 + 16 * i;
        s = 1;
    } else {
        int u = t - 64;
        bool lvl2 = (u >= 48);
        if (lvl2) u -= 48;
        int i, j;
        if (u < 16) {              // rows 0,1 full
            i = u >> 3; j = u & 7;
        } else if (u < 32) {       // rows 2..5, cols 0,1,6,7
            int v = u - 16;
            i = 2 + (v >> 2);
            int p = v & 3;
            j = (p < 2) ? p : (p + 4);
        } else {                   // rows 6,7 full
            int v = u - 32;
            i = 6 + (v >> 3); j = v & 7;
        }
        if (!lvl2) { cx = 128 + 32 * j; cy = 128 + 32 * i; s = 2; }
        else       { cx = 64 * j;       cy = 64 * i;       s = 4; }
    }
}

__global__ __launch_bounds__(256) void fovea_kernel(const float* __restrict__ img,
                                                    float* __restrict__ out) {
    int idx = blockIdx.x * 256 + threadIdx.x;
    // idx = (((b*NTOK + t)*NC + c)*16 + i)*16 + j
    int j  = idx & 15;
    int i  = (idx >> 4) & 15;
    int c  = (idx >> 8) % NC;
    int bt = idx / (NC * 256);
    int t  = bt % NTOK;
    int b  = bt / NTOK;

    int cx, cy, s;
    token_params(t, cx, cy, s);

    const float* base = img + ((size_t)(b * NC + c) << 18);  // 512*512 = 1<<18
    int x0 = cx + s * j;
    int y0 = cy + s * i;

    float sum;
    if (s == 1) {
        sum = base[(y0 << 9) + x0];
    } else if (s == 2) {
        sum = 0.f;
        #pragma unroll
        for (int dy = 0; dy < 2; ++dy) {
            const float2 v = *reinterpret_cast<const float2*>(base + ((size_t)(y0 + dy) << 9) + x0);
            sum += v.x + v.y;
        }
        sum *= 0.25f;
    } else {
        sum = 0.f;
        #pragma unroll
        for (int dy = 0; dy < 4; ++dy) {
            const float4 v = *reinterpret_cast<const float4*>(base + ((size_t)(y0 + dy) << 9) + x0);
            sum += v.x + v.y + v.z + v.w;
        }
        sum *= 0.0625f;
    }
    out[idx] = sum;
}

extern "C" void kernel_launch(void* const* d_in, const int* in_sizes, int n_in,
                              void* d_out, int out_size, void* d_ws, size_t ws_size,
                              hipStream_t stream) {
    const float* img = (const float*)d_in[0];
    float* out = (float*)d_out;
    // out_size = 32*160*3*16*16 = 3,932,160
    int total = NB * NTOK * NC * 16 * 16;
    int blocks = total / 256;  // 15360
    fovea_kernel<<<blocks, 256, 0, stream>>>(img, out);
}